// Round 1
// baseline (244.054 us; speedup 1.0000x reference)
//
#include <hip/hip_runtime.h>

#define BATCH 32
#define LQ 1024
#define DIM 128
#define QT 16
#define NW 8
#define NT 512

typedef __attribute__((ext_vector_type(8))) short bf16x8;
typedef __attribute__((ext_vector_type(4))) float f32x4;

// fp32 -> bf16 bits, round-to-nearest-even (no header-type dependence)
__device__ __forceinline__ unsigned short f2bf(float f) {
  unsigned u = __float_as_uint(f);
  return (unsigned short)((u + 0x7fffu + ((u >> 16) & 1u)) >> 16);
}

__device__ __forceinline__ bf16x8 cvt8(f32x4 a, f32x4 b) {
  bf16x8 r;
  r[0] = (short)f2bf(a[0]); r[1] = (short)f2bf(a[1]);
  r[2] = (short)f2bf(a[2]); r[3] = (short)f2bf(a[3]);
  r[4] = (short)f2bf(b[0]); r[5] = (short)f2bf(b[1]);
  r[6] = (short)f2bf(b[2]); r[7] = (short)f2bf(b[3]);
  return r;
}

__global__ __launch_bounds__(NT)
void dsma_kernel(const float* __restrict__ Qp, const float* __restrict__ Kp,
                 const float* __restrict__ Vp, const float* __restrict__ Sp,
                 const float* __restrict__ Gp, float* __restrict__ Op)
{
  // 64 KB LDS total: W (32KB) | V-chunk transpose buffer, unioned with
  // reduction scratch (32KB)
  __shared__ __align__(16) char smem[65536];
  unsigned short* Wlds = (unsigned short*)smem;           // [QT][LQ] bf16, swizzled
  unsigned short* Vt   = (unsigned short*)(smem + 32768); // [DIM][128] bf16, swizzled
  float (*red)[NW][QT] = (float (*)[NW][QT])(smem + 32768); // aliases Vt (phases 2-3 only)

  const int tid  = (int)threadIdx.x;
  const int lane = tid & 63;
  const int wid  = tid >> 6;       // wave 0..7
  const int g4   = lane >> 4;      // 16-lane group 0..3
  const int ll   = lane & 15;
  const int b    = (int)blockIdx.y;
  const int qbase = (int)blockIdx.x * QT;

  const float scale = Sp[0];
  const float* Qb = Qp + ((size_t)b * LQ + qbase) * DIM;
  const float* Kb = Kp + (size_t)b * LQ * DIM;
  const float* Vb = Vp + (size_t)b * LQ * DIM;
  const float* Gb = Gp + ((size_t)b * LQ + qbase) * (size_t)LQ;

  // ---- Q fragments (A-operand): row = ll, k-dim d = dc*32 + g4*8 + j.
  // Pre-scale by `scale` so S = (scale*Q)K^T directly.
  bf16x8 qf[4];
  {
    const float* qp = Qb + (size_t)ll * DIM + g4 * 8;
    #pragma unroll
    for (int dc = 0; dc < 4; ++dc) {
      f32x4 a = *(const f32x4*)(qp + dc * 32);
      f32x4 c = *(const f32x4*)(qp + dc * 32 + 4);
      a *= scale; c *= scale;
      qf[dc] = cvt8(a, c);
    }
  }

  // ---- Phase 1: S strip (16 rows x 128 cols per wave), resident in regs.
  // C-layout: value S[g4*4+r][cb0 + s*16 + ll] in S[s][r].
  f32x4 S[8];
  #pragma unroll
  for (int s = 0; s < 8; ++s) { S[s][0]=0.f; S[s][1]=0.f; S[s][2]=0.f; S[s][3]=0.f; }
  const int cb0 = wid * 128;
  #pragma unroll
  for (int s = 0; s < 8; ++s) {
    const float* kp = Kb + (size_t)(cb0 + s * 16 + ll) * DIM + g4 * 8;
    #pragma unroll
    for (int dc = 0; dc < 4; ++dc) {
      f32x4 a = *(const f32x4*)(kp + dc * 32);
      f32x4 c = *(const f32x4*)(kp + dc * 32 + 4);
      bf16x8 kf = cvt8(a, c);
      S[s] = __builtin_amdgcn_mfma_f32_16x16x32_bf16(qf[dc], kf, S[s], 0, 0, 0);
    }
  }

  // ---- Phase 2: softmax1 row stats (m1, 1/l1). Row r of lane = g4*4+r.
  float vmax[4] = {-1e30f, -1e30f, -1e30f, -1e30f};
  #pragma unroll
  for (int s = 0; s < 8; ++s)
    #pragma unroll
    for (int r = 0; r < 4; ++r) vmax[r] = fmaxf(vmax[r], S[s][r]);
  #pragma unroll
  for (int m = 1; m <= 8; m <<= 1) {
    #pragma unroll
    for (int r = 0; r < 4; ++r)
      vmax[r] = fmaxf(vmax[r], __shfl_xor(vmax[r], m, 64));
  }
  if (ll == 0) {
    #pragma unroll
    for (int r = 0; r < 4; ++r) red[0][wid][g4 * 4 + r] = vmax[r];
  }
  __syncthreads();
  float m1[4];
  #pragma unroll
  for (int r = 0; r < 4; ++r) {
    float m = -1e30f;
    #pragma unroll
    for (int w = 0; w < NW; ++w) m = fmaxf(m, red[0][w][g4 * 4 + r]);
    m1[r] = m;
  }
  float vsum[4] = {0.f, 0.f, 0.f, 0.f};
  #pragma unroll
  for (int s = 0; s < 8; ++s)
    #pragma unroll
    for (int r = 0; r < 4; ++r) {
      float e = __expf(S[s][r] - m1[r]);
      S[s][r] = e;               // keep exp(s-m1) in place
      vsum[r] += e;
    }
  #pragma unroll
  for (int m = 1; m <= 8; m <<= 1) {
    #pragma unroll
    for (int r = 0; r < 4; ++r) vsum[r] += __shfl_xor(vsum[r], m, 64);
  }
  if (ll == 0) {
    #pragma unroll
    for (int r = 0; r < 4; ++r) red[1][wid][g4 * 4 + r] = vsum[r];
  }
  __syncthreads();
  float l1i[4];
  #pragma unroll
  for (int r = 0; r < 4; ++r) {
    float t = 0.f;
    #pragma unroll
    for (int w = 0; w < NW; ++w) t += red[1][w][g4 * 4 + r];
    l1i[r] = 1.0f / t;
  }

  // ---- Phase 3: beta = p1*g, w = exp(beta) (beta in [0,~0.06]: no max
  // subtraction needed), store W to LDS (bf16, XOR-swizzled), l2 partials.
  float vs2[4] = {0.f, 0.f, 0.f, 0.f};
  #pragma unroll
  for (int s = 0; s < 8; ++s) {
    const int col = cb0 + s * 16 + ll;
    #pragma unroll
    for (int r = 0; r < 4; ++r) {
      const int row = g4 * 4 + r;
      float g = Gb[(size_t)row * LQ + col];
      float w = __expf(S[s][r] * l1i[r] * g);
      vs2[r] += w;
      int byt = row * (LQ * 2) + col * 2;
      byt ^= (row & 7) << 4;
      *(unsigned short*)((char*)Wlds + byt) = f2bf(w);
    }
  }
  #pragma unroll
  for (int m = 1; m <= 8; m <<= 1) {
    #pragma unroll
    for (int r = 0; r < 4; ++r) vs2[r] += __shfl_xor(vs2[r], m, 64);
  }
  if (ll == 0) {
    #pragma unroll
    for (int r = 0; r < 4; ++r) red[0][wid][g4 * 4 + r] = vs2[r];
  }
  __syncthreads();   // W complete + l2 partials complete
  float l2i[4];
  #pragma unroll
  for (int r = 0; r < 4; ++r) {
    float t = 0.f;
    #pragma unroll
    for (int w = 0; w < NW; ++w) t += red[0][w][g4 * 4 + r];
    l2i[r] = 1.0f / t;
  }

  // ---- Phase 4: O = W V. Wave computes d-subtile [wid*16, wid*16+16).
  // V chunk (128 k-rows) transposed+cast into LDS per iteration.
  f32x4 acc = {0.f, 0.f, 0.f, 0.f};
  const int dsub = wid * 16;
  for (int c = 0; c < 8; ++c) {
    __syncthreads();  // previous chunk's reads done (also fences l2i reads, c=0)
    #pragma unroll
    for (int i = 0; i < 4; ++i) {
      int pi  = tid + i * NT;   // 0..2047
      int krp = pi >> 5;        // k-row pair 0..63
      int dq  = pi & 31;        // float4 index along d
      const float* vp = Vb + (size_t)(c * 128 + krp * 2) * DIM + dq * 4;
      f32x4 v0 = *(const f32x4*)vp;
      f32x4 v1 = *(const f32x4*)(vp + DIM);
      #pragma unroll
      for (int dd = 0; dd < 4; ++dd) {
        int d = dq * 4 + dd;
        int byt = d * 256 + krp * 4;   // byte = d*256 + 2*k (k = 2*krp)
        byt ^= (d & 7) << 4;
        unsigned pk = (unsigned)f2bf(v0[dd]) | ((unsigned)f2bf(v1[dd]) << 16);
        *(unsigned*)((char*)Vt + byt) = pk;
      }
    }
    __syncthreads();
    #pragma unroll
    for (int kc = 0; kc < 4; ++kc) {
      // A-frag: W[row=ll][k = c*128 + kc*32 + g4*8 ..+8]
      int abyt = ll * (LQ * 2) + (c * 128 + kc * 32 + g4 * 8) * 2;
      abyt ^= (ll & 7) << 4;
      bf16x8 af = *(const bf16x8*)((const char*)Wlds + abyt);
      // B-frag: V^T[d = dsub+ll][k = kc*32 + g4*8 ..+8]
      int brow = dsub + ll;
      int bbyt = brow * 256 + (kc * 32 + g4 * 8) * 2;
      bbyt ^= (brow & 7) << 4;
      bf16x8 vf = *(const bf16x8*)((const char*)Vt + bbyt);
      acc = __builtin_amdgcn_mfma_f32_16x16x32_bf16(af, vf, acc, 0, 0, 0);
    }
  }

  // ---- Epilogue: normalize by l2 and store (row = g4*4+r matches l2i[r]).
  #pragma unroll
  for (int r = 0; r < 4; ++r) {
    int row = g4 * 4 + r;
    Op[((size_t)b * LQ + qbase + row) * DIM + dsub + ll] = acc[r] * l2i[r];
  }
}

extern "C" void kernel_launch(void* const* d_in, const int* in_sizes, int n_in,
                              void* d_out, int out_size, void* d_ws, size_t ws_size,
                              hipStream_t stream) {
  const float* Q = (const float*)d_in[0];
  const float* K = (const float*)d_in[1];
  const float* V = (const float*)d_in[2];
  const float* s = (const float*)d_in[3];
  const float* G = (const float*)d_in[4];
  float* O = (float*)d_out;
  dim3 grid(LQ / QT, BATCH);
  dsma_kernel<<<grid, NT, 0, stream>>>(Q, K, V, s, G, O);
}